// Round 4
// baseline (459.900 us; speedup 1.0000x reference)
//
#include <hip/hip_runtime.h>
#include <stdint.h>

// Shapes: B=2, L=1024 -> BLT=2048 tokens; D_MODEL=512, D_INNER=1024, DT_RANK=32, D_STATE=16
#define BLT 2048
#define DMODEL 512
#define DINNER 1024
#define TCH 8  // tokens per thread in ssm_fuse_k

typedef __bf16 bf16x8 __attribute__((ext_vector_type(8)));
typedef float f32x4 __attribute__((ext_vector_type(4)));

// ---------------- MFMA GEMM: C[m,n] = sum_k A[m,k] * B[n,k], f32 in/out ----------------
// BM=128, BN=128, BK=64. 256 threads = 4 waves arranged 2x2, wave tile 64x64.
// (kept for reference/fallback; currently unused by the launcher)
__global__ __launch_bounds__(256) void gemm_mfma(const float* __restrict__ A,
                                                 const float* __restrict__ B,
                                                 float* __restrict__ C,
                                                 int M, int N, int K) {
    __shared__ __bf16 As[128][72];
    __shared__ __bf16 Bs[128][72];
    const int tid = threadIdx.x;
    const int wave = tid >> 6, lane = tid & 63;
    const int waveM = wave >> 1, waveN = wave & 1;
    const int quad = lane >> 4, l16 = lane & 15;
    const int m0 = blockIdx.y * 128, n0 = blockIdx.x * 128;

    f32x4 acc[4][4];
#pragma unroll
    for (int mi = 0; mi < 4; mi++)
#pragma unroll
        for (int ni = 0; ni < 4; ni++) acc[mi][ni] = (f32x4){0.f, 0.f, 0.f, 0.f};

    const int sr = tid >> 4;
    const int sc = (tid & 15) * 4;

    for (int k0 = 0; k0 < K; k0 += 64) {
#pragma unroll
        for (int p = 0; p < 8; p++) {
            int r = sr + p * 16;
            float4 v = *(const float4*)(A + (size_t)(m0 + r) * K + k0 + sc);
            union { __bf16 b[4]; uint2 u; } pk;
            pk.b[0] = (__bf16)v.x; pk.b[1] = (__bf16)v.y;
            pk.b[2] = (__bf16)v.z; pk.b[3] = (__bf16)v.w;
            *(uint2*)&As[r][sc] = pk.u;
        }
#pragma unroll
        for (int p = 0; p < 8; p++) {
            int r = sr + p * 16;
            float4 v = *(const float4*)(B + (size_t)(n0 + r) * K + k0 + sc);
            union { __bf16 b[4]; uint2 u; } pk;
            pk.b[0] = (__bf16)v.x; pk.b[1] = (__bf16)v.y;
            pk.b[2] = (__bf16)v.z; pk.b[3] = (__bf16)v.w;
            *(uint2*)&Bs[r][sc] = pk.u;
        }
        __syncthreads();
#pragma unroll
        for (int kk = 0; kk < 64; kk += 32) {
            bf16x8 af[4], bfr[4];
#pragma unroll
            for (int mi = 0; mi < 4; mi++)
                af[mi] = *(const bf16x8*)&As[waveM * 64 + mi * 16 + l16][kk + quad * 8];
#pragma unroll
            for (int ni = 0; ni < 4; ni++)
                bfr[ni] = *(const bf16x8*)&Bs[waveN * 64 + ni * 16 + l16][kk + quad * 8];
#pragma unroll
            for (int mi = 0; mi < 4; mi++)
#pragma unroll
                for (int ni = 0; ni < 4; ni++)
                    acc[mi][ni] = __builtin_amdgcn_mfma_f32_16x16x32_bf16(
                        af[mi], bfr[ni], acc[mi][ni], 0, 0, 0);
        }
        __syncthreads();
    }
#pragma unroll
    for (int mi = 0; mi < 4; mi++)
#pragma unroll
        for (int ni = 0; ni < 4; ni++)
#pragma unroll
            for (int reg = 0; reg < 4; reg++) {
                int m = m0 + waveM * 64 + mi * 16 + quad * 4 + reg;
                int n = n0 + waveN * 64 + ni * 16 + l16;
                C[(size_t)m * N + n] = acc[mi][ni][reg];
            }
}

// ---------------- 64x64-tile MFMA GEMM (same fragment mapping, 4x the blocks) ----------
// BM=64, BN=64, BK=64. 256 threads = 4 waves arranged 2x2, wave tile 32x32.
__global__ __launch_bounds__(256) void gemm_mfma_64(const float* __restrict__ A,
                                                    const float* __restrict__ B,
                                                    float* __restrict__ C,
                                                    int M, int N, int K) {
    __shared__ __bf16 As[64][72];
    __shared__ __bf16 Bs[64][72];
    const int tid = threadIdx.x;
    const int wave = tid >> 6, lane = tid & 63;
    const int waveM = wave >> 1, waveN = wave & 1;
    const int quad = lane >> 4, l16 = lane & 15;
    const int m0 = blockIdx.y * 64, n0 = blockIdx.x * 64;

    f32x4 acc[2][2];
#pragma unroll
    for (int mi = 0; mi < 2; mi++)
#pragma unroll
        for (int ni = 0; ni < 2; ni++) acc[mi][ni] = (f32x4){0.f, 0.f, 0.f, 0.f};

    const int sr = tid >> 4;
    const int sc = (tid & 15) * 4;

    for (int k0 = 0; k0 < K; k0 += 64) {
#pragma unroll
        for (int p = 0; p < 4; p++) {
            int r = sr + p * 16;
            float4 v = *(const float4*)(A + (size_t)(m0 + r) * K + k0 + sc);
            union { __bf16 b[4]; uint2 u; } pk;
            pk.b[0] = (__bf16)v.x; pk.b[1] = (__bf16)v.y;
            pk.b[2] = (__bf16)v.z; pk.b[3] = (__bf16)v.w;
            *(uint2*)&As[r][sc] = pk.u;
        }
#pragma unroll
        for (int p = 0; p < 4; p++) {
            int r = sr + p * 16;
            float4 v = *(const float4*)(B + (size_t)(n0 + r) * K + k0 + sc);
            union { __bf16 b[4]; uint2 u; } pk;
            pk.b[0] = (__bf16)v.x; pk.b[1] = (__bf16)v.y;
            pk.b[2] = (__bf16)v.z; pk.b[3] = (__bf16)v.w;
            *(uint2*)&Bs[r][sc] = pk.u;
        }
        __syncthreads();
#pragma unroll
        for (int kk = 0; kk < 64; kk += 32) {
            bf16x8 af[2], bfr[2];
#pragma unroll
            for (int mi = 0; mi < 2; mi++)
                af[mi] = *(const bf16x8*)&As[waveM * 32 + mi * 16 + l16][kk + quad * 8];
#pragma unroll
            for (int ni = 0; ni < 2; ni++)
                bfr[ni] = *(const bf16x8*)&Bs[waveN * 32 + ni * 16 + l16][kk + quad * 8];
#pragma unroll
            for (int mi = 0; mi < 2; mi++)
#pragma unroll
                for (int ni = 0; ni < 2; ni++)
                    acc[mi][ni] = __builtin_amdgcn_mfma_f32_16x16x32_bf16(
                        af[mi], bfr[ni], acc[mi][ni], 0, 0, 0);
        }
        __syncthreads();
    }
#pragma unroll
    for (int mi = 0; mi < 2; mi++)
#pragma unroll
        for (int ni = 0; ni < 2; ni++)
#pragma unroll
            for (int reg = 0; reg < 4; reg++) {
                int m = m0 + waveM * 32 + mi * 16 + quad * 4 + reg;
                int n = n0 + waveN * 32 + ni * 16 + l16;
                C[(size_t)m * N + n] = acc[mi][ni][reg];
            }
}

// -------- small-M MFMA GEMM with split-K: BM=32, BN=64, K-chunk per blockIdx.z --------
__global__ __launch_bounds__(256) void gemm_mfma_s_splitk(const float* __restrict__ A,
                                                          const float* __restrict__ B,
                                                          float* __restrict__ Cpart,
                                                          int M, int N, int K, int kchunk) {
    __shared__ __bf16 As[32][72];
    __shared__ __bf16 Bs[64][72];
    const int tid = threadIdx.x;
    const int wave = tid >> 6, lane = tid & 63;
    const int waveM = wave >> 1, waveN = wave & 1;
    const int quad = lane >> 4, l16 = lane & 15;
    const int m0 = blockIdx.y * 32, n0 = blockIdx.x * 64;
    const int kbeg = blockIdx.z * kchunk;
    const int kend = kbeg + kchunk;

    f32x4 acc[2];
    acc[0] = (f32x4){0.f, 0.f, 0.f, 0.f};
    acc[1] = (f32x4){0.f, 0.f, 0.f, 0.f};

    const int sr = tid >> 4;
    const int sc = (tid & 15) * 4;

    for (int k0 = kbeg; k0 < kend; k0 += 64) {
#pragma unroll
        for (int p = 0; p < 2; p++) {
            int r = sr + p * 16;
            float4 v = *(const float4*)(A + (size_t)(m0 + r) * K + k0 + sc);
            union { __bf16 b[4]; uint2 u; } pk;
            pk.b[0] = (__bf16)v.x; pk.b[1] = (__bf16)v.y;
            pk.b[2] = (__bf16)v.z; pk.b[3] = (__bf16)v.w;
            *(uint2*)&As[r][sc] = pk.u;
        }
#pragma unroll
        for (int p = 0; p < 4; p++) {
            int r = sr + p * 16;
            float4 v = *(const float4*)(B + (size_t)(n0 + r) * K + k0 + sc);
            union { __bf16 b[4]; uint2 u; } pk;
            pk.b[0] = (__bf16)v.x; pk.b[1] = (__bf16)v.y;
            pk.b[2] = (__bf16)v.z; pk.b[3] = (__bf16)v.w;
            *(uint2*)&Bs[r][sc] = pk.u;
        }
        __syncthreads();
#pragma unroll
        for (int kk = 0; kk < 64; kk += 32) {
            bf16x8 af = *(const bf16x8*)&As[waveM * 16 + l16][kk + quad * 8];
#pragma unroll
            for (int ni = 0; ni < 2; ni++) {
                bf16x8 bf = *(const bf16x8*)&Bs[waveN * 32 + ni * 16 + l16][kk + quad * 8];
                acc[ni] = __builtin_amdgcn_mfma_f32_16x16x32_bf16(af, bf, acc[ni], 0, 0, 0);
            }
        }
        __syncthreads();
    }
    float* Cz = Cpart + (size_t)blockIdx.z * M * N;
#pragma unroll
    for (int ni = 0; ni < 2; ni++)
#pragma unroll
        for (int reg = 0; reg < 4; reg++) {
            int m = m0 + waveM * 16 + quad * 4 + reg;
            int n = n0 + waveN * 32 + ni * 16 + l16;
            Cz[(size_t)m * N + n] = acc[ni][reg];
        }
}

// ---------- prep: dtwT[r][d] = dtw[d][r] ; Aneg = -exp(A_log) ----------
__global__ __launch_bounds__(256) void prep_k(const float* __restrict__ dtw,   // [1024,32]
                                              const float* __restrict__ A_log, // [1024,16]
                                              float* __restrict__ dtwT,        // [32,1024]
                                              float* __restrict__ Aneg) {      // [1024,16]
    int i = blockIdx.x * 256 + threadIdx.x;  // grid 128 -> 32768 threads
    {   // dtwT: 32768 elems
        int r = i >> 10, d = i & 1023;
        dtwT[i] = dtw[d * 32 + r];
    }
    if (i < 16384) Aneg[i] = -__expf(A_log[i]);
}

// ---------- depthwise conv1d (K=3, SAME pad over L within each batch) + SiLU ----------
__global__ __launch_bounds__(256) void conv1d_silu_k(const float* __restrict__ xz,
                                                     const float* __restrict__ w,
                                                     const float* __restrict__ bias,
                                                     float* __restrict__ xs) {
    int idx = blockIdx.x * 256 + threadIdx.x;  // t*1024 + d
    int t = idx >> 10, d = idx & 1023;
    int l = t & 1023;
    float cur = xz[(size_t)t * 2048 + d];
    float prev = (l > 0) ? xz[(size_t)(t - 1) * 2048 + d] : 0.f;
    float nxt = (l < 1023) ? xz[(size_t)(t + 1) * 2048 + d] : 0.f;
    float v = w[d * 3] * prev + w[d * 3 + 1] * cur + w[d * 3 + 2] * nxt + bias[d];
    xs[idx] = v / (1.f + __expf(-v));
}

// ---- SSM step + 4x4 state convs + y.Cm + D*xs + y*silu(z), t-chunked ----
// Each thread owns one d and iterates TCH tokens, holding all per-d constants
// (dtwT column, Aneg, conv weights) in registers. dBC rows for the chunk are
// staged in LDS once (summing the 4 split-K partials).
__global__ __launch_bounds__(256) void ssm_fuse_k(
    const float* __restrict__ h,       // [BLT,1024,16]
    const float* __restrict__ xz,      // [BLT,2048] (z in cols 1024..2047)
    const float* __restrict__ xs,      // [BLT,1024]
    const float* __restrict__ dBCp,    // [4][BLT,64] partials (0:32 dt-rank, 32:48 B, 48:64 C)
    const float* __restrict__ dtwT,    // [32,1024]
    const float* __restrict__ dtb,     // [1024]
    const float* __restrict__ Aneg,    // [1024,16]
    const float* __restrict__ Dp,      // [1024]
    const float* __restrict__ sf1w, const float* __restrict__ sf1b,
    const float* __restrict__ sf2w, const float* __restrict__ sf2b,
    const float* __restrict__ alpha,
    float* __restrict__ hn_out,        // [BLT,1024,16] (output 1)
    float* __restrict__ yz) {          // [BLT,1024]
    const int tid = threadIdx.x;
    const int d = blockIdx.x * 256 + tid;
    const int t0 = blockIdx.y * TCH;

    __shared__ float dbc_s[TCH * 64];
    {
        const size_t base = (size_t)t0 * 64;
        const size_t st = (size_t)BLT * 64;
#pragma unroll
        for (int i = tid; i < TCH * 64; i += 256) {
            const size_t o = base + i;
            dbc_s[i] = dBCp[o] + dBCp[o + st] + dBCp[o + 2 * st] + dBCp[o + 3 * st];
        }
    }
    __syncthreads();

    // ---- per-d constants, loaded once and held in registers ----
    float dtw_r[32];
#pragma unroll
    for (int r = 0; r < 32; r++) dtw_r[r] = dtwT[r * 1024 + d];
    float an[16];
    {
        const float4* apv = (const float4*)(Aneg + (size_t)d * 16);
#pragma unroll
        for (int q = 0; q < 4; q++) {
            float4 aq = apv[q];
            an[q * 4 + 0] = aq.x; an[q * 4 + 1] = aq.y;
            an[q * 4 + 2] = aq.z; an[q * 4 + 3] = aq.w;
        }
    }
    float w2[9];
#pragma unroll
    for (int k = 0; k < 9; k++) w2[k] = sf2w[d * 9 + k];
    const float w1 = sf1w[d], b1 = sf1b[d], b2v = sf2b[d];
    const float a0f = alpha[0], a1f = alpha[1];
    const float dtb_d = dtb[d], Dp_d = Dp[d];

#pragma unroll
    for (int tt = 0; tt < TCH; tt++) {
        const int t = t0 + tt;
        const size_t td = (size_t)t * 1024 + d;
        // streaming loads for this token
        const float xv = xs[td];
        const float zv = xz[(size_t)t * 2048 + 1024 + d];
        float hv[16];
        {
            const float4* hp = (const float4*)(h + td * 16);
#pragma unroll
            for (int q = 0; q < 4; q++) {
                float4 hq = hp[q];
                hv[q * 4 + 0] = hq.x; hv[q * 4 + 1] = hq.y;
                hv[q * 4 + 2] = hq.z; hv[q * 4 + 3] = hq.w;
            }
        }
        // delta = softplus(dbc[0:32] . dtw_r + dtb)
        float accd = dtb_d;
#pragma unroll
        for (int r = 0; r < 32; r++) accd += dbc_s[tt * 64 + r] * dtw_r[r];
        const float dt = (accd > 20.f) ? accd : __logf(1.f + __expf(accd));
        const float dx = dt * xv;

        float hn[16];
#pragma unroll
        for (int s = 0; s < 16; s++)
            hn[s] = __expf(dt * an[s]) * hv[s] + dx * dbc_s[tt * 64 + 32 + s];

        // state fusion: alpha0*(1x1 dw conv) + alpha1*(3x3 dw conv, pad 1) on 4x4 grid
        float hf[16];
#pragma unroll
        for (int i = 0; i < 4; i++)
#pragma unroll
            for (int j = 0; j < 4; j++) {
                float s2 = b2v;
#pragma unroll
                for (int ki = 0; ki < 3; ki++)
#pragma unroll
                    for (int kj = 0; kj < 3; kj++) {
                        int ii = i + ki - 1, jj = j + kj - 1;
                        if (ii >= 0 && ii < 4 && jj >= 0 && jj < 4)
                            s2 += hn[ii * 4 + jj] * w2[ki * 3 + kj];
                    }
                hf[i * 4 + j] = a0f * (w1 * hn[i * 4 + j] + b1) + a1f * s2;
            }
        float y = Dp_d * xv;
#pragma unroll
        for (int s = 0; s < 16; s++) y += hf[s] * dbc_s[tt * 64 + 48 + s];
        yz[td] = y * (zv / (1.f + __expf(-zv)));
        // hn_out written once, never read again: non-temporal stores (ext-vector type —
        // __builtin_nontemporal_store rejects HIP's float4 struct type)
        f32x4* op = (f32x4*)(hn_out + td * 16);
#pragma unroll
        for (int q = 0; q < 4; q++) {
            f32x4 v4 = (f32x4){hf[q * 4 + 0], hf[q * 4 + 1], hf[q * 4 + 2], hf[q * 4 + 3]};
            __builtin_nontemporal_store(v4, op + q);
        }
    }
}

extern "C" void kernel_launch(void* const* d_in, const int* in_sizes, int n_in,
                              void* d_out, int out_size, void* d_ws, size_t ws_size,
                              hipStream_t stream) {
    const float* x         = (const float*)d_in[0];
    const float* h         = (const float*)d_in[1];
    const float* in_proj_w = (const float*)d_in[2];
    const float* conv1d_w  = (const float*)d_in[3];
    const float* conv1d_b  = (const float*)d_in[4];
    const float* x_proj_w  = (const float*)d_in[5];
    const float* dt_proj_w = (const float*)d_in[6];
    const float* dt_proj_b = (const float*)d_in[7];
    const float* A_log     = (const float*)d_in[8];
    const float* Dp        = (const float*)d_in[9];
    const float* sf1w      = (const float*)d_in[10];
    const float* sf1b      = (const float*)d_in[11];
    const float* sf2w      = (const float*)d_in[12];
    const float* sf2b      = (const float*)d_in[13];
    const float* alpha     = (const float*)d_in[14];
    const float* out_projw = (const float*)d_in[15];

    float* out0   = (float*)d_out;                    // [2048,512]
    float* hn_out = out0 + (size_t)BLT * DMODEL;      // [2048,1024,16]

    // workspace (f32): ~36 MB
    float* xz   = (float*)d_ws;                       // [2048,2048]
    float* xs   = xz + (size_t)BLT * 2048;            // [2048,1024]
    float* dBCp = xs + (size_t)BLT * DINNER;          // [4][2048,64] split-K partials
    float* yz   = dBCp + (size_t)4 * BLT * 64;        // [2048,1024]
    float* dtwT = yz + (size_t)BLT * DINNER;          // [32,1024]
    float* Aneg = dtwT + 32 * 1024;                   // [1024,16]

    // 0) prep: dtw transpose + Aneg = -exp(A_log)
    prep_k<<<128, 256, 0, stream>>>(dt_proj_w, A_log, dtwT, Aneg);
    // 1) in_proj: xz = x @ in_proj_w^T (M=2048, N=2048, K=512) — 64x64 tiles: 1024 blocks
    gemm_mfma_64<<<dim3(2048 / 64, BLT / 64), 256, 0, stream>>>(x, in_proj_w, xz,
                                                                BLT, 2048, DMODEL);
    // 2) depthwise conv1d + silu -> xs
    conv1d_silu_k<<<(BLT * DINNER) / 256, 256, 0, stream>>>(xz, conv1d_w, conv1d_b, xs);
    // 3) dBC = xs @ x_proj_w^T (M=2048, N=64, K=1024) — split-K x4: 256 blocks
    gemm_mfma_s_splitk<<<dim3(1, BLT / 32, 4), 256, 0, stream>>>(xs, x_proj_w, dBCp,
                                                                 BLT, 64, DINNER, 256);
    // 4) SSM step + state fusion + gating -> hn_out, yz (t-chunked, consts in regs)
    ssm_fuse_k<<<dim3(4, BLT / TCH), 256, 0, stream>>>(h, xz, xs, dBCp, dtwT, dt_proj_b,
                                                       Aneg, Dp, sf1w, sf1b, sf2w, sf2b, alpha,
                                                       hn_out, yz);
    // 5) out = yz @ out_proj_w^T (M=2048, N=512, K=1024) — 64x64 tiles: 256 blocks
    gemm_mfma_64<<<dim3(DMODEL / 64, BLT / 64), 256, 0, stream>>>(yz, out_projw, out0,
                                                                  BLT, DMODEL, DINNER);
}

// Round 6
// 396.970 us; speedup vs baseline: 1.1585x; 1.1585x over previous
//
#include <hip/hip_runtime.h>
#include <stdint.h>

// Shapes: B=2, L=1024 -> BLT=2048 tokens; D_MODEL=512, D_INNER=1024, DT_RANK=32, D_STATE=16
#define BLT 2048
#define DMODEL 512
#define DINNER 1024
#define TCH 2  // tokens per thread in ssm_fuse_k (TCH=8 regressed: occupancy cliff)

typedef __bf16 bf16x8 __attribute__((ext_vector_type(8)));
typedef float f32x4 __attribute__((ext_vector_type(4)));

// ---------------- 64x64-tile MFMA GEMM: C[m,n] = sum_k A[m,k]*B[n,k] ----------------
// BM=64, BN=64, BK=64. 256 threads = 4 waves arranged 2x2, wave tile 32x32.
// XCD-aware bijective swizzle (nwg % 8 == 0 at both call sites): each XCD gets a
// contiguous tile strip -> B-panel reuse inside its private 4 MB L2.
__global__ __launch_bounds__(256) void gemm_mfma_64(const float* __restrict__ A,
                                                    const float* __restrict__ B,
                                                    float* __restrict__ C,
                                                    int M, int N, int K) {
    __shared__ __bf16 As[64][72];
    __shared__ __bf16 Bs[64][72];
    const int tid = threadIdx.x;
    const int wave = tid >> 6, lane = tid & 63;
    const int waveM = wave >> 1, waveN = wave & 1;
    const int quad = lane >> 4, l16 = lane & 15;

    // XCD swizzle: dispatcher assigns consecutive bids round-robin to XCDs;
    // remap so XCD k computes a contiguous tile range.
    const int nwg = gridDim.x * gridDim.y;
    const int bid = blockIdx.y * gridDim.x + blockIdx.x;
    const int cpx = nwg >> 3;                    // nwg % 8 == 0 guaranteed
    const int swz = (bid & 7) * cpx + (bid >> 3);
    const int bx = swz % gridDim.x, by = swz / gridDim.x;
    const int m0 = by * 64, n0 = bx * 64;

    f32x4 acc[2][2];
#pragma unroll
    for (int mi = 0; mi < 2; mi++)
#pragma unroll
        for (int ni = 0; ni < 2; ni++) acc[mi][ni] = (f32x4){0.f, 0.f, 0.f, 0.f};

    const int sr = tid >> 4;
    const int sc = (tid & 15) * 4;

    for (int k0 = 0; k0 < K; k0 += 64) {
#pragma unroll
        for (int p = 0; p < 4; p++) {
            int r = sr + p * 16;
            float4 v = *(const float4*)(A + (size_t)(m0 + r) * K + k0 + sc);
            union { __bf16 b[4]; uint2 u; } pk;
            pk.b[0] = (__bf16)v.x; pk.b[1] = (__bf16)v.y;
            pk.b[2] = (__bf16)v.z; pk.b[3] = (__bf16)v.w;
            *(uint2*)&As[r][sc] = pk.u;
        }
#pragma unroll
        for (int p = 0; p < 4; p++) {
            int r = sr + p * 16;
            float4 v = *(const float4*)(B + (size_t)(n0 + r) * K + k0 + sc);
            union { __bf16 b[4]; uint2 u; } pk;
            pk.b[0] = (__bf16)v.x; pk.b[1] = (__bf16)v.y;
            pk.b[2] = (__bf16)v.z; pk.b[3] = (__bf16)v.w;
            *(uint2*)&Bs[r][sc] = pk.u;
        }
        __syncthreads();
#pragma unroll
        for (int kk = 0; kk < 64; kk += 32) {
            bf16x8 af[2], bfr[2];
#pragma unroll
            for (int mi = 0; mi < 2; mi++)
                af[mi] = *(const bf16x8*)&As[waveM * 32 + mi * 16 + l16][kk + quad * 8];
#pragma unroll
            for (int ni = 0; ni < 2; ni++)
                bfr[ni] = *(const bf16x8*)&Bs[waveN * 32 + ni * 16 + l16][kk + quad * 8];
#pragma unroll
            for (int mi = 0; mi < 2; mi++)
#pragma unroll
                for (int ni = 0; ni < 2; ni++)
                    acc[mi][ni] = __builtin_amdgcn_mfma_f32_16x16x32_bf16(
                        af[mi], bfr[ni], acc[mi][ni], 0, 0, 0);
        }
        __syncthreads();
    }
#pragma unroll
    for (int mi = 0; mi < 2; mi++)
#pragma unroll
        for (int ni = 0; ni < 2; ni++)
#pragma unroll
            for (int reg = 0; reg < 4; reg++) {
                int m = m0 + waveM * 32 + mi * 16 + quad * 4 + reg;
                int n = n0 + waveN * 32 + ni * 16 + l16;
                C[(size_t)m * N + n] = acc[mi][ni][reg];
            }
}

// -------- small-M MFMA GEMM with split-K: BM=32, BN=64, K-chunk per blockIdx.z --------
__global__ __launch_bounds__(256) void gemm_mfma_s_splitk(const float* __restrict__ A,
                                                          const float* __restrict__ B,
                                                          float* __restrict__ Cpart,
                                                          int M, int N, int K, int kchunk) {
    __shared__ __bf16 As[32][72];
    __shared__ __bf16 Bs[64][72];
    const int tid = threadIdx.x;
    const int wave = tid >> 6, lane = tid & 63;
    const int waveM = wave >> 1, waveN = wave & 1;
    const int quad = lane >> 4, l16 = lane & 15;
    const int m0 = blockIdx.y * 32, n0 = blockIdx.x * 64;
    const int kbeg = blockIdx.z * kchunk;
    const int kend = kbeg + kchunk;

    f32x4 acc[2];
    acc[0] = (f32x4){0.f, 0.f, 0.f, 0.f};
    acc[1] = (f32x4){0.f, 0.f, 0.f, 0.f};

    const int sr = tid >> 4;
    const int sc = (tid & 15) * 4;

    for (int k0 = kbeg; k0 < kend; k0 += 64) {
#pragma unroll
        for (int p = 0; p < 2; p++) {
            int r = sr + p * 16;
            float4 v = *(const float4*)(A + (size_t)(m0 + r) * K + k0 + sc);
            union { __bf16 b[4]; uint2 u; } pk;
            pk.b[0] = (__bf16)v.x; pk.b[1] = (__bf16)v.y;
            pk.b[2] = (__bf16)v.z; pk.b[3] = (__bf16)v.w;
            *(uint2*)&As[r][sc] = pk.u;
        }
#pragma unroll
        for (int p = 0; p < 4; p++) {
            int r = sr + p * 16;
            float4 v = *(const float4*)(B + (size_t)(n0 + r) * K + k0 + sc);
            union { __bf16 b[4]; uint2 u; } pk;
            pk.b[0] = (__bf16)v.x; pk.b[1] = (__bf16)v.y;
            pk.b[2] = (__bf16)v.z; pk.b[3] = (__bf16)v.w;
            *(uint2*)&Bs[r][sc] = pk.u;
        }
        __syncthreads();
#pragma unroll
        for (int kk = 0; kk < 64; kk += 32) {
            bf16x8 af = *(const bf16x8*)&As[waveM * 16 + l16][kk + quad * 8];
#pragma unroll
            for (int ni = 0; ni < 2; ni++) {
                bf16x8 bf = *(const bf16x8*)&Bs[waveN * 32 + ni * 16 + l16][kk + quad * 8];
                acc[ni] = __builtin_amdgcn_mfma_f32_16x16x32_bf16(af, bf, acc[ni], 0, 0, 0);
            }
        }
        __syncthreads();
    }
    float* Cz = Cpart + (size_t)blockIdx.z * M * N;
#pragma unroll
    for (int ni = 0; ni < 2; ni++)
#pragma unroll
        for (int reg = 0; reg < 4; reg++) {
            int m = m0 + waveM * 16 + quad * 4 + reg;
            int n = n0 + waveN * 32 + ni * 16 + l16;
            Cz[(size_t)m * N + n] = acc[ni][reg];
        }
}

// ---------- prep: dtwT[r][d] = dtw[d][r] ; Aneg = -exp(A_log) ----------
__global__ __launch_bounds__(256) void prep_k(const float* __restrict__ dtw,   // [1024,32]
                                              const float* __restrict__ A_log, // [1024,16]
                                              float* __restrict__ dtwT,        // [32,1024]
                                              float* __restrict__ Aneg) {      // [1024,16]
    int i = blockIdx.x * 256 + threadIdx.x;  // grid 128 -> 32768 threads
    {   // dtwT: 32768 elems
        int r = i >> 10, d = i & 1023;
        dtwT[i] = dtw[d * 32 + r];
    }
    if (i < 16384) Aneg[i] = -__expf(A_log[i]);
}

// ---------- depthwise conv1d (K=3, SAME pad over L within each batch) + SiLU ----------
__global__ __launch_bounds__(256) void conv1d_silu_k(const float* __restrict__ xz,
                                                     const float* __restrict__ w,
                                                     const float* __restrict__ bias,
                                                     float* __restrict__ xs) {
    int idx = blockIdx.x * 256 + threadIdx.x;  // t*1024 + d
    int t = idx >> 10, d = idx & 1023;
    int l = t & 1023;
    float cur = xz[(size_t)t * 2048 + d];
    float prev = (l > 0) ? xz[(size_t)(t - 1) * 2048 + d] : 0.f;
    float nxt = (l < 1023) ? xz[(size_t)(t + 1) * 2048 + d] : 0.f;
    float v = w[d * 3] * prev + w[d * 3 + 1] * cur + w[d * 3 + 2] * nxt + bias[d];
    xs[idx] = v / (1.f + __expf(-v));
}

// ---- SSM step + 4x4 state convs + y.Cm + D*xs + y*silu(z), TCH=2 tokens/thread ----
// Per-d constants (dtwT column, Aneg, conv weights) loaded once, reused for 2 tokens.
// Plain stores (NO nontemporal: round-4 showed nt on partial-line patterns amplifies
// WRITE_SIZE 143->243 MB). Grid 4096 blocks keeps occupancy high.
__global__ __launch_bounds__(256) void ssm_fuse_k(
    const float* __restrict__ h,       // [BLT,1024,16]
    const float* __restrict__ xz,      // [BLT,2048] (z in cols 1024..2047)
    const float* __restrict__ xs,      // [BLT,1024]
    const float* __restrict__ dBCp,    // [4][BLT,64] partials (0:32 dt-rank, 32:48 B, 48:64 C)
    const float* __restrict__ dtwT,    // [32,1024]
    const float* __restrict__ dtb,     // [1024]
    const float* __restrict__ Aneg,    // [1024,16]
    const float* __restrict__ Dp,      // [1024]
    const float* __restrict__ sf1w, const float* __restrict__ sf1b,
    const float* __restrict__ sf2w, const float* __restrict__ sf2b,
    const float* __restrict__ alpha,
    float* __restrict__ hn_out,        // [BLT,1024,16] (output 1)
    float* __restrict__ yz) {          // [BLT,1024]
    const int tid = threadIdx.x;
    const int d = blockIdx.x * 256 + tid;
    const int t0 = blockIdx.y * TCH;

    __shared__ float dbc_s[TCH * 64];
    if (tid < TCH * 64) {
        const size_t o = (size_t)t0 * 64 + tid;
        const size_t st = (size_t)BLT * 64;
        dbc_s[tid] = dBCp[o] + dBCp[o + st] + dBCp[o + 2 * st] + dBCp[o + 3 * st];
    }
    __syncthreads();

    // ---- per-d constants, loaded once and held in registers ----
    float dtw_r[32];
#pragma unroll
    for (int r = 0; r < 32; r++) dtw_r[r] = dtwT[r * 1024 + d];
    float an[16];
    {
        const float4* apv = (const float4*)(Aneg + (size_t)d * 16);
#pragma unroll
        for (int q = 0; q < 4; q++) {
            float4 aq = apv[q];
            an[q * 4 + 0] = aq.x; an[q * 4 + 1] = aq.y;
            an[q * 4 + 2] = aq.z; an[q * 4 + 3] = aq.w;
        }
    }
    float w2[9];
#pragma unroll
    for (int k = 0; k < 9; k++) w2[k] = sf2w[d * 9 + k];
    const float w1 = sf1w[d], b1 = sf1b[d], b2v = sf2b[d];
    const float a0f = alpha[0], a1f = alpha[1];
    const float dtb_d = dtb[d], Dp_d = Dp[d];

#pragma unroll
    for (int tt = 0; tt < TCH; tt++) {
        const int t = t0 + tt;
        const size_t td = (size_t)t * 1024 + d;
        // streaming loads for this token
        const float xv = xs[td];
        const float zv = xz[(size_t)t * 2048 + 1024 + d];
        float hv[16];
        {
            const float4* hp = (const float4*)(h + td * 16);
#pragma unroll
            for (int q = 0; q < 4; q++) {
                float4 hq = hp[q];
                hv[q * 4 + 0] = hq.x; hv[q * 4 + 1] = hq.y;
                hv[q * 4 + 2] = hq.z; hv[q * 4 + 3] = hq.w;
            }
        }
        // delta = softplus(dbc[0:32] . dtw_r + dtb)
        float accd = dtb_d;
#pragma unroll
        for (int r = 0; r < 32; r++) accd += dbc_s[tt * 64 + r] * dtw_r[r];
        const float dt = (accd > 20.f) ? accd : __logf(1.f + __expf(accd));
        const float dx = dt * xv;

        float hn[16];
#pragma unroll
        for (int s = 0; s < 16; s++)
            hn[s] = __expf(dt * an[s]) * hv[s] + dx * dbc_s[tt * 64 + 32 + s];

        // state fusion: alpha0*(1x1 dw conv) + alpha1*(3x3 dw conv, pad 1) on 4x4 grid
        float hf[16];
#pragma unroll
        for (int i = 0; i < 4; i++)
#pragma unroll
            for (int j = 0; j < 4; j++) {
                float s2 = b2v;
#pragma unroll
                for (int ki = 0; ki < 3; ki++)
#pragma unroll
                    for (int kj = 0; kj < 3; kj++) {
                        int ii = i + ki - 1, jj = j + kj - 1;
                        if (ii >= 0 && ii < 4 && jj >= 0 && jj < 4)
                            s2 += hn[ii * 4 + jj] * w2[ki * 3 + kj];
                    }
                hf[i * 4 + j] = a0f * (w1 * hn[i * 4 + j] + b1) + a1f * s2;
            }
        float y = Dp_d * xv;
#pragma unroll
        for (int s = 0; s < 16; s++) y += hf[s] * dbc_s[tt * 64 + 48 + s];
        yz[td] = y * (zv / (1.f + __expf(-zv)));
        float4* op = (float4*)(hn_out + td * 16);
#pragma unroll
        for (int q = 0; q < 4; q++)
            op[q] = make_float4(hf[q * 4 + 0], hf[q * 4 + 1], hf[q * 4 + 2], hf[q * 4 + 3]);
    }
}

extern "C" void kernel_launch(void* const* d_in, const int* in_sizes, int n_in,
                              void* d_out, int out_size, void* d_ws, size_t ws_size,
                              hipStream_t stream) {
    const float* x         = (const float*)d_in[0];
    const float* h         = (const float*)d_in[1];
    const float* in_proj_w = (const float*)d_in[2];
    const float* conv1d_w  = (const float*)d_in[3];
    const float* conv1d_b  = (const float*)d_in[4];
    const float* x_proj_w  = (const float*)d_in[5];
    const float* dt_proj_w = (const float*)d_in[6];
    const float* dt_proj_b = (const float*)d_in[7];
    const float* A_log     = (const float*)d_in[8];
    const float* Dp        = (const float*)d_in[9];
    const float* sf1w      = (const float*)d_in[10];
    const float* sf1b      = (const float*)d_in[11];
    const float* sf2w      = (const float*)d_in[12];
    const float* sf2b      = (const float*)d_in[13];
    const float* alpha     = (const float*)d_in[14];
    const float* out_projw = (const float*)d_in[15];

    float* out0   = (float*)d_out;                    // [2048,512]
    float* hn_out = out0 + (size_t)BLT * DMODEL;      // [2048,1024,16]

    // workspace (f32): ~36 MB
    float* xz   = (float*)d_ws;                       // [2048,2048]
    float* xs   = xz + (size_t)BLT * 2048;            // [2048,1024]
    float* dBCp = xs + (size_t)BLT * DINNER;          // [4][2048,64] split-K partials
    float* yz   = dBCp + (size_t)4 * BLT * 64;        // [2048,1024]
    float* dtwT = yz + (size_t)BLT * DINNER;          // [32,1024]
    float* Aneg = dtwT + 32 * 1024;                   // [1024,16]

    // 0) prep: dtw transpose + Aneg = -exp(A_log)
    prep_k<<<128, 256, 0, stream>>>(dt_proj_w, A_log, dtwT, Aneg);
    // 1) in_proj: xz = x @ in_proj_w^T (M=2048, N=2048, K=512) — 1024 blocks, XCD-swizzled
    gemm_mfma_64<<<dim3(2048 / 64, BLT / 64), 256, 0, stream>>>(x, in_proj_w, xz,
                                                                BLT, 2048, DMODEL);
    // 2) depthwise conv1d + silu -> xs
    conv1d_silu_k<<<(BLT * DINNER) / 256, 256, 0, stream>>>(xz, conv1d_w, conv1d_b, xs);
    // 3) dBC = xs @ x_proj_w^T (M=2048, N=64, K=1024) — split-K x4: 256 blocks
    gemm_mfma_s_splitk<<<dim3(1, BLT / 32, 4), 256, 0, stream>>>(xs, x_proj_w, dBCp,
                                                                 BLT, 64, DINNER, 256);
    // 4) SSM step + state fusion + gating -> hn_out, yz (TCH=2, consts in regs)
    ssm_fuse_k<<<dim3(4, BLT / TCH), 256, 0, stream>>>(h, xz, xs, dBCp, dtwT, dt_proj_b,
                                                       Aneg, Dp, sf1w, sf1b, sf2w, sf2b, alpha,
                                                       hn_out, yz);
    // 5) out = yz @ out_proj_w^T (M=2048, N=512, K=1024) — 256 blocks, XCD-swizzled
    gemm_mfma_64<<<dim3(DMODEL / 64, BLT / 64), 256, 0, stream>>>(yz, out_projw, out0,
                                                                  BLT, DMODEL, DINNER);
}

// Round 7
// 396.952 us; speedup vs baseline: 1.1586x; 1.0000x over previous
//
#include <hip/hip_runtime.h>
#include <stdint.h>

// Shapes: B=2, L=1024 -> BLT=2048 tokens; D_MODEL=512, D_INNER=1024, DT_RANK=32, D_STATE=16
#define BLT 2048
#define DMODEL 512
#define DINNER 1024
#define TCH 4  // tokens per block-row in ssm_fuse_k

typedef __bf16 bf16x8 __attribute__((ext_vector_type(8)));
typedef float f32x4 __attribute__((ext_vector_type(4)));

// ---------------- 64x64-tile MFMA GEMM: C[m,n] = sum_k A[m,k]*B[n,k] ----------------
// BM=64, BN=64, BK=64. 256 threads = 4 waves arranged 2x2, wave tile 32x32.
// XCD-aware bijective swizzle (nwg % 8 == 0 at both call sites).
__global__ __launch_bounds__(256) void gemm_mfma_64(const float* __restrict__ A,
                                                    const float* __restrict__ B,
                                                    float* __restrict__ C,
                                                    int M, int N, int K) {
    __shared__ __bf16 As[64][72];
    __shared__ __bf16 Bs[64][72];
    const int tid = threadIdx.x;
    const int wave = tid >> 6, lane = tid & 63;
    const int waveM = wave >> 1, waveN = wave & 1;
    const int quad = lane >> 4, l16 = lane & 15;

    const int nwg = gridDim.x * gridDim.y;
    const int bid = blockIdx.y * gridDim.x + blockIdx.x;
    const int cpx = nwg >> 3;                    // nwg % 8 == 0 guaranteed
    const int swz = (bid & 7) * cpx + (bid >> 3);
    const int bx = swz % gridDim.x, by = swz / gridDim.x;
    const int m0 = by * 64, n0 = bx * 64;

    f32x4 acc[2][2];
#pragma unroll
    for (int mi = 0; mi < 2; mi++)
#pragma unroll
        for (int ni = 0; ni < 2; ni++) acc[mi][ni] = (f32x4){0.f, 0.f, 0.f, 0.f};

    const int sr = tid >> 4;
    const int sc = (tid & 15) * 4;

    for (int k0 = 0; k0 < K; k0 += 64) {
#pragma unroll
        for (int p = 0; p < 4; p++) {
            int r = sr + p * 16;
            float4 v = *(const float4*)(A + (size_t)(m0 + r) * K + k0 + sc);
            union { __bf16 b[4]; uint2 u; } pk;
            pk.b[0] = (__bf16)v.x; pk.b[1] = (__bf16)v.y;
            pk.b[2] = (__bf16)v.z; pk.b[3] = (__bf16)v.w;
            *(uint2*)&As[r][sc] = pk.u;
        }
#pragma unroll
        for (int p = 0; p < 4; p++) {
            int r = sr + p * 16;
            float4 v = *(const float4*)(B + (size_t)(n0 + r) * K + k0 + sc);
            union { __bf16 b[4]; uint2 u; } pk;
            pk.b[0] = (__bf16)v.x; pk.b[1] = (__bf16)v.y;
            pk.b[2] = (__bf16)v.z; pk.b[3] = (__bf16)v.w;
            *(uint2*)&Bs[r][sc] = pk.u;
        }
        __syncthreads();
#pragma unroll
        for (int kk = 0; kk < 64; kk += 32) {
            bf16x8 af[2], bfr[2];
#pragma unroll
            for (int mi = 0; mi < 2; mi++)
                af[mi] = *(const bf16x8*)&As[waveM * 32 + mi * 16 + l16][kk + quad * 8];
#pragma unroll
            for (int ni = 0; ni < 2; ni++)
                bfr[ni] = *(const bf16x8*)&Bs[waveN * 32 + ni * 16 + l16][kk + quad * 8];
#pragma unroll
            for (int mi = 0; mi < 2; mi++)
#pragma unroll
                for (int ni = 0; ni < 2; ni++)
                    acc[mi][ni] = __builtin_amdgcn_mfma_f32_16x16x32_bf16(
                        af[mi], bfr[ni], acc[mi][ni], 0, 0, 0);
        }
        __syncthreads();
    }
#pragma unroll
    for (int mi = 0; mi < 2; mi++)
#pragma unroll
        for (int ni = 0; ni < 2; ni++)
#pragma unroll
            for (int reg = 0; reg < 4; reg++) {
                int m = m0 + waveM * 32 + mi * 16 + quad * 4 + reg;
                int n = n0 + waveN * 32 + ni * 16 + l16;
                C[(size_t)m * N + n] = acc[mi][ni][reg];
            }
}

// -------- small-M MFMA GEMM with split-K: BM=32, BN=64, K-chunk per blockIdx.z --------
__global__ __launch_bounds__(256) void gemm_mfma_s_splitk(const float* __restrict__ A,
                                                          const float* __restrict__ B,
                                                          float* __restrict__ Cpart,
                                                          int M, int N, int K, int kchunk) {
    __shared__ __bf16 As[32][72];
    __shared__ __bf16 Bs[64][72];
    const int tid = threadIdx.x;
    const int wave = tid >> 6, lane = tid & 63;
    const int waveM = wave >> 1, waveN = wave & 1;
    const int quad = lane >> 4, l16 = lane & 15;
    const int m0 = blockIdx.y * 32, n0 = blockIdx.x * 64;
    const int kbeg = blockIdx.z * kchunk;
    const int kend = kbeg + kchunk;

    f32x4 acc[2];
    acc[0] = (f32x4){0.f, 0.f, 0.f, 0.f};
    acc[1] = (f32x4){0.f, 0.f, 0.f, 0.f};

    const int sr = tid >> 4;
    const int sc = (tid & 15) * 4;

    for (int k0 = kbeg; k0 < kend; k0 += 64) {
#pragma unroll
        for (int p = 0; p < 2; p++) {
            int r = sr + p * 16;
            float4 v = *(const float4*)(A + (size_t)(m0 + r) * K + k0 + sc);
            union { __bf16 b[4]; uint2 u; } pk;
            pk.b[0] = (__bf16)v.x; pk.b[1] = (__bf16)v.y;
            pk.b[2] = (__bf16)v.z; pk.b[3] = (__bf16)v.w;
            *(uint2*)&As[r][sc] = pk.u;
        }
#pragma unroll
        for (int p = 0; p < 4; p++) {
            int r = sr + p * 16;
            float4 v = *(const float4*)(B + (size_t)(n0 + r) * K + k0 + sc);
            union { __bf16 b[4]; uint2 u; } pk;
            pk.b[0] = (__bf16)v.x; pk.b[1] = (__bf16)v.y;
            pk.b[2] = (__bf16)v.z; pk.b[3] = (__bf16)v.w;
            *(uint2*)&Bs[r][sc] = pk.u;
        }
        __syncthreads();
#pragma unroll
        for (int kk = 0; kk < 64; kk += 32) {
            bf16x8 af = *(const bf16x8*)&As[waveM * 16 + l16][kk + quad * 8];
#pragma unroll
            for (int ni = 0; ni < 2; ni++) {
                bf16x8 bf = *(const bf16x8*)&Bs[waveN * 32 + ni * 16 + l16][kk + quad * 8];
                acc[ni] = __builtin_amdgcn_mfma_f32_16x16x32_bf16(af, bf, acc[ni], 0, 0, 0);
            }
        }
        __syncthreads();
    }
    float* Cz = Cpart + (size_t)blockIdx.z * M * N;
#pragma unroll
    for (int ni = 0; ni < 2; ni++)
#pragma unroll
        for (int reg = 0; reg < 4; reg++) {
            int m = m0 + waveM * 16 + quad * 4 + reg;
            int n = n0 + waveN * 32 + ni * 16 + l16;
            Cz[(size_t)m * N + n] = acc[ni][reg];
        }
}

// ---------- prep: Aneg = -exp(A_log) (dtwT transpose no longer needed) ----------
__global__ __launch_bounds__(256) void prep_k(const float* __restrict__ A_log, // [1024,16]
                                              float* __restrict__ Aneg) {      // [1024,16]
    int i = blockIdx.x * 256 + threadIdx.x;  // grid 64 -> 16384 threads
    if (i < 16384) Aneg[i] = -__expf(A_log[i]);
}

// ---------- depthwise conv1d (K=3, SAME pad over L per batch) + SiLU, float4 ----------
__global__ __launch_bounds__(256) void conv1d_silu_k(const float* __restrict__ xz,
                                                     const float* __restrict__ w,
                                                     const float* __restrict__ bias,
                                                     float* __restrict__ xs) {
    int idx = blockIdx.x * 256 + threadIdx.x;  // t*256 + d4 (4 d's per thread)
    int t = idx >> 8, d0 = (idx & 255) * 4;
    int l = t & 1023;
    const float4 cur = *(const float4*)(xz + (size_t)t * 2048 + d0);
    float4 prev = make_float4(0.f, 0.f, 0.f, 0.f);
    float4 nxt = make_float4(0.f, 0.f, 0.f, 0.f);
    if (l > 0)    prev = *(const float4*)(xz + (size_t)(t - 1) * 2048 + d0);
    if (l < 1023) nxt  = *(const float4*)(xz + (size_t)(t + 1) * 2048 + d0);
    const float4 bv = *(const float4*)(bias + d0);
    // w is [d][3] row-major: 12 contiguous floats for 4 consecutive d
    const float4 wa = *(const float4*)(w + d0 * 3);      // d0:{0,1,2}, d0+1:{0}
    const float4 wb = *(const float4*)(w + d0 * 3 + 4);  // d0+1:{1,2}, d0+2:{0,1}
    const float4 wc = *(const float4*)(w + d0 * 3 + 8);  // d0+2:{2}, d0+3:{0,1,2}
    float pr[4] = {prev.x, prev.y, prev.z, prev.w};
    float cu[4] = {cur.x, cur.y, cur.z, cur.w};
    float nx[4] = {nxt.x, nxt.y, nxt.z, nxt.w};
    float bb[4] = {bv.x, bv.y, bv.z, bv.w};
    float wf[12] = {wa.x, wa.y, wa.z, wa.w, wb.x, wb.y, wb.z, wb.w, wc.x, wc.y, wc.z, wc.w};
    float out[4];
#pragma unroll
    for (int j = 0; j < 4; j++) {
        float v = wf[j * 3] * pr[j] + wf[j * 3 + 1] * cu[j] + wf[j * 3 + 2] * nx[j] + bb[j];
        out[j] = v / (1.f + __expf(-v));
    }
    *(float4*)(xs + (size_t)t * 1024 + d0) = make_float4(out[0], out[1], out[2], out[3]);
}

// ---- SSM step + 4x4 state convs + y.Cm + D*xs + y*silu(z), TCH=4, dtw in LDS ----
// Block owns 256 d's x 4 tokens. dtw panel (256x32) staged in LDS from dt_proj_w's
// naturally-contiguous [d][32] layout (coalesced float4 loads, padded [256][33] rows
// -> conflict-free reads: bank = (tid + r) % 32, all lanes distinct).
// launch_bounds(256,4) pins >=4 waves/SIMD (VGPR cap 128) so occupancy can't cliff.
__global__ __launch_bounds__(256, 4) void ssm_fuse_k(
    const float* __restrict__ h,       // [BLT,1024,16]
    const float* __restrict__ xz,      // [BLT,2048] (z in cols 1024..2047)
    const float* __restrict__ xs,      // [BLT,1024]
    const float* __restrict__ dBCp,    // [4][BLT,64] partials (0:32 dt-rank, 32:48 B, 48:64 C)
    const float* __restrict__ dtw,     // [1024,32] dt_proj_w (row-major, d-major)
    const float* __restrict__ dtb,     // [1024]
    const float* __restrict__ Aneg,    // [1024,16]
    const float* __restrict__ Dp,      // [1024]
    const float* __restrict__ sf1w, const float* __restrict__ sf1b,
    const float* __restrict__ sf2w, const float* __restrict__ sf2b,
    const float* __restrict__ alpha,
    float* __restrict__ hn_out,        // [BLT,1024,16] (output 1)
    float* __restrict__ yz) {          // [BLT,1024]
    const int tid = threadIdx.x;
    const int d0b = blockIdx.x * 256;
    const int d = d0b + tid;
    const int t0 = blockIdx.y * TCH;

    __shared__ float dtw_s[256][33];   // 33.8 KB, padded for conflict-free reads
    __shared__ float dbc_s[TCH * 64];  // 1 KB

    // dbc stage: tid covers exactly TCH*64 = 256 entries; sum the 4 split-K partials
    {
        const size_t o = (size_t)t0 * 64 + tid;
        const size_t st = (size_t)BLT * 64;
        dbc_s[tid] = dBCp[o] + dBCp[o + st] + dBCp[o + 2 * st] + dBCp[o + 3 * st];
    }
    // dtw stage: block slice is contiguous [d0b*32 .. +8192) floats; 8 float4/thread
    {
        const float4* src = (const float4*)(dtw + (size_t)d0b * 32);
#pragma unroll
        for (int c = 0; c < 8; c++) {
            int f4 = c * 256 + tid;
            float4 v = src[f4];
            int dl = f4 >> 3;            // 8 float4 per 32-float row
            int r0 = (f4 & 7) << 2;
            float* wp = &dtw_s[dl][r0];
            wp[0] = v.x; wp[1] = v.y; wp[2] = v.z; wp[3] = v.w;
        }
    }
    __syncthreads();

    // ---- per-d constants in registers (fits: ~32 regs) ----
    float an[16];
    {
        const float4* apv = (const float4*)(Aneg + (size_t)d * 16);
#pragma unroll
        for (int q = 0; q < 4; q++) {
            float4 aq = apv[q];
            an[q * 4 + 0] = aq.x; an[q * 4 + 1] = aq.y;
            an[q * 4 + 2] = aq.z; an[q * 4 + 3] = aq.w;
        }
    }
    float w2[9];
#pragma unroll
    for (int k = 0; k < 9; k++) w2[k] = sf2w[d * 9 + k];
    const float w1 = sf1w[d], b1 = sf1b[d], b2v = sf2b[d];
    const float a0f = alpha[0], a1f = alpha[1];
    const float dtb_d = dtb[d], Dp_d = Dp[d];

#pragma unroll
    for (int tt = 0; tt < TCH; tt++) {
        const int t = t0 + tt;
        const size_t td = (size_t)t * 1024 + d;
        const float xv = xs[td];
        const float zv = xz[(size_t)t * 2048 + 1024 + d];
        float hv[16];
        {
            const float4* hp = (const float4*)(h + td * 16);
#pragma unroll
            for (int q = 0; q < 4; q++) {
                float4 hq = hp[q];
                hv[q * 4 + 0] = hq.x; hv[q * 4 + 1] = hq.y;
                hv[q * 4 + 2] = hq.z; hv[q * 4 + 3] = hq.w;
            }
        }
        // delta = softplus(dbc[0:32] . dtw[d,:] + dtb) — dtw from LDS, conflict-free
        float accd = dtb_d;
#pragma unroll
        for (int r = 0; r < 32; r++) accd += dbc_s[tt * 64 + r] * dtw_s[tid][r];
        const float dt = (accd > 20.f) ? accd : __logf(1.f + __expf(accd));
        const float dx = dt * xv;

        float hn[16];
#pragma unroll
        for (int s = 0; s < 16; s++)
            hn[s] = __expf(dt * an[s]) * hv[s] + dx * dbc_s[tt * 64 + 32 + s];

        // state fusion: alpha0*(1x1 dw conv) + alpha1*(3x3 dw conv, pad 1) on 4x4 grid
        float hf[16];
#pragma unroll
        for (int i = 0; i < 4; i++)
#pragma unroll
            for (int j = 0; j < 4; j++) {
                float s2 = b2v;
#pragma unroll
                for (int ki = 0; ki < 3; ki++)
#pragma unroll
                    for (int kj = 0; kj < 3; kj++) {
                        int ii = i + ki - 1, jj = j + kj - 1;
                        if (ii >= 0 && ii < 4 && jj >= 0 && jj < 4)
                            s2 += hn[ii * 4 + jj] * w2[ki * 3 + kj];
                    }
                hf[i * 4 + j] = a0f * (w1 * hn[i * 4 + j] + b1) + a1f * s2;
            }
        float y = Dp_d * xv;
#pragma unroll
        for (int s = 0; s < 16; s++) y += hf[s] * dbc_s[tt * 64 + 48 + s];
        yz[td] = y * (zv / (1.f + __expf(-zv)));
        float4* op = (float4*)(hn_out + td * 16);
#pragma unroll
        for (int q = 0; q < 4; q++)
            op[q] = make_float4(hf[q * 4 + 0], hf[q * 4 + 1], hf[q * 4 + 2], hf[q * 4 + 3]);
    }
}

extern "C" void kernel_launch(void* const* d_in, const int* in_sizes, int n_in,
                              void* d_out, int out_size, void* d_ws, size_t ws_size,
                              hipStream_t stream) {
    const float* x         = (const float*)d_in[0];
    const float* h         = (const float*)d_in[1];
    const float* in_proj_w = (const float*)d_in[2];
    const float* conv1d_w  = (const float*)d_in[3];
    const float* conv1d_b  = (const float*)d_in[4];
    const float* x_proj_w  = (const float*)d_in[5];
    const float* dt_proj_w = (const float*)d_in[6];
    const float* dt_proj_b = (const float*)d_in[7];
    const float* A_log     = (const float*)d_in[8];
    const float* Dp        = (const float*)d_in[9];
    const float* sf1w      = (const float*)d_in[10];
    const float* sf1b      = (const float*)d_in[11];
    const float* sf2w      = (const float*)d_in[12];
    const float* sf2b      = (const float*)d_in[13];
    const float* alpha     = (const float*)d_in[14];
    const float* out_projw = (const float*)d_in[15];

    float* out0   = (float*)d_out;                    // [2048,512]
    float* hn_out = out0 + (size_t)BLT * DMODEL;      // [2048,1024,16]

    // workspace (f32): ~36 MB
    float* xz   = (float*)d_ws;                       // [2048,2048]
    float* xs   = xz + (size_t)BLT * 2048;            // [2048,1024]
    float* dBCp = xs + (size_t)BLT * DINNER;          // [4][2048,64] split-K partials
    float* yz   = dBCp + (size_t)4 * BLT * 64;        // [2048,1024]
    float* Aneg = yz + (size_t)BLT * DINNER;          // [1024,16]

    // 0) prep: Aneg = -exp(A_log)
    prep_k<<<64, 256, 0, stream>>>(A_log, Aneg);
    // 1) in_proj: xz = x @ in_proj_w^T (M=2048, N=2048, K=512) — 1024 blocks, XCD-swizzled
    gemm_mfma_64<<<dim3(2048 / 64, BLT / 64), 256, 0, stream>>>(x, in_proj_w, xz,
                                                                BLT, 2048, DMODEL);
    // 2) depthwise conv1d + silu -> xs (float4: 4 d's per thread)
    conv1d_silu_k<<<(BLT * DINNER / 4) / 256, 256, 0, stream>>>(xz, conv1d_w, conv1d_b, xs);
    // 3) dBC = xs @ x_proj_w^T (M=2048, N=64, K=1024) — split-K x4: 256 blocks
    gemm_mfma_s_splitk<<<dim3(1, BLT / 32, 4), 256, 0, stream>>>(xs, x_proj_w, dBCp,
                                                                 BLT, 64, DINNER, 256);
    // 4) SSM step + state fusion + gating -> hn_out, yz (TCH=4, dtw panel in LDS)
    ssm_fuse_k<<<dim3(4, BLT / TCH), 256, 0, stream>>>(h, xz, xs, dBCp, dt_proj_w, dt_proj_b,
                                                       Aneg, Dp, sf1w, sf1b, sf2w, sf2b, alpha,
                                                       hn_out, yz);
    // 5) out = yz @ out_proj_w^T (M=2048, N=512, K=1024) — 256 blocks, XCD-swizzled
    gemm_mfma_64<<<dim3(DMODEL / 64, BLT / 64), 256, 0, stream>>>(yz, out_projw, out0,
                                                                  BLT, DMODEL, DINNER);
}